// Round 3
// baseline (1294.359 us; speedup 1.0000x reference)
//
#include <hip/hip_runtime.h>
#include <math.h>

#define SCAN_B 1024

// ---------------- CSR build ----------------

__global__ void zero_counts_kernel(int* __restrict__ c, int n) {
    int i = blockIdx.x * blockDim.x + threadIdx.x;
    if (i < n) c[i] = 0;
}

__global__ void hist_kernel(const int* __restrict__ dst, int* __restrict__ counts, int e) {
    int i = blockIdx.x * blockDim.x + threadIdx.x;
    if (i < e) atomicAdd(&counts[dst[i]], 1);
}

// dis[i] = rsqrt(deg_in + 1)   (self-loop included)
__global__ void dis_kernel(const int* __restrict__ counts, float* __restrict__ dis, int n) {
    int i = blockIdx.x * blockDim.x + threadIdx.x;
    if (i < n) dis[i] = rsqrtf((float)counts[i] + 1.0f);
}

// block-local exclusive scan of counts -> rowptr ; block totals -> bsums
__global__ void scan1_kernel(const int* __restrict__ counts, int* __restrict__ rowptr,
                             int* __restrict__ bsums, int n) {
    __shared__ int tmp[SCAN_B];
    int tid = threadIdx.x;
    int i = blockIdx.x * SCAN_B + tid;
    int v = (i < n) ? counts[i] : 0;
    tmp[tid] = v;
    __syncthreads();
    #pragma unroll
    for (int off = 1; off < SCAN_B; off <<= 1) {
        int t = (tid >= off) ? tmp[tid - off] : 0;
        __syncthreads();
        tmp[tid] += t;
        __syncthreads();
    }
    if (i < n) rowptr[i] = tmp[tid] - v;          // exclusive within block
    if (tid == SCAN_B - 1) bsums[blockIdx.x] = tmp[tid];
}

// single-block exclusive scan of bsums (nb <= SCAN_B)
__global__ void scan2_kernel(int* __restrict__ bsums, int nb) {
    __shared__ int tmp[SCAN_B];
    int tid = threadIdx.x;
    int v = (tid < nb) ? bsums[tid] : 0;
    tmp[tid] = v;
    __syncthreads();
    #pragma unroll
    for (int off = 1; off < SCAN_B; off <<= 1) {
        int t = (tid >= off) ? tmp[tid - off] : 0;
        __syncthreads();
        tmp[tid] += t;
        __syncthreads();
    }
    if (tid < nb) bsums[tid] = tmp[tid] - v;
}

// add block offsets; copy to fill-cursor array; write rowptr[n]=e
__global__ void scan3_kernel(int* __restrict__ rowptr, int* __restrict__ next,
                             const int* __restrict__ bsums, int n, int e) {
    int i = blockIdx.x * blockDim.x + threadIdx.x;
    if (i < n) {
        int r = rowptr[i] + bsums[i / SCAN_B];
        rowptr[i] = r;
        next[i] = r;
    }
    if (i == 0) rowptr[n] = e;
}

// bucket-fill: srcs sorted by dst, plus per-edge normalized weight
__global__ void fill_kernel(const int* __restrict__ src, const int* __restrict__ dst,
                            int* __restrict__ next, const float* __restrict__ dis,
                            int* __restrict__ srcs, float* __restrict__ wn, int e) {
    int i = blockIdx.x * blockDim.x + threadIdx.x;
    if (i < e) {
        int s = src[i], d = dst[i];
        int pos = atomicAdd(&next[d], 1);
        srcs[pos] = s;
        wn[pos] = dis[s] * dis[d];
    }
}

// ---------------- register-tiled GEMM: Y[n,OUT] = X[n,IN] @ W[IN,OUT] (+bias) ----------------
// block = 256 threads -> 64 rows x 64 (padded) cols; thread = 4x4 tile.

template<int IN_F, int OUT_F, bool BIAS>
__global__ __launch_bounds__(256) void gemm_tile_kernel(const float* __restrict__ X,
                                                        const float* __restrict__ W,
                                                        const float* __restrict__ bias,
                                                        float* __restrict__ Y, int n) {
    constexpr int PC = 64;  // padded col count
    __shared__ float Wl[IN_F * PC];
    int tid = threadIdx.x;
    for (int idx = tid; idx < IN_F * PC; idx += 256) {
        int k = idx / PC, c = idx % PC;
        Wl[idx] = (c < OUT_F) ? W[k * OUT_F + c] : 0.f;
    }
    __syncthreads();
    int tx = tid & 15;   // col group (4 cols)
    int ty = tid >> 4;   // row group (4 rows)
    int r0 = blockIdx.x * 64 + ty * 4;
    int c0 = tx * 4;
    float acc[4][4] = {};
    const float4* Wv = (const float4*)Wl;  // index: k*16 + tx
    for (int k = 0; k < IN_F; k += 4) {
        float4 xv[4];
        #pragma unroll
        for (int i = 0; i < 4; ++i) {
            int r = r0 + i;
            xv[i] = (r < n) ? *(const float4*)(X + (size_t)r * IN_F + k)
                            : make_float4(0.f, 0.f, 0.f, 0.f);
        }
        #pragma unroll
        for (int j = 0; j < 4; ++j) {
            float4 wv = Wv[(k + j) * 16 + tx];
            #pragma unroll
            for (int i = 0; i < 4; ++i) {
                float xs = (j == 0) ? xv[i].x : (j == 1) ? xv[i].y : (j == 2) ? xv[i].z : xv[i].w;
                acc[i][0] = fmaf(xs, wv.x, acc[i][0]);
                acc[i][1] = fmaf(xs, wv.y, acc[i][1]);
                acc[i][2] = fmaf(xs, wv.z, acc[i][2]);
                acc[i][3] = fmaf(xs, wv.w, acc[i][3]);
            }
        }
    }
    if (c0 < OUT_F) {
        float4 bb = make_float4(0.f, 0.f, 0.f, 0.f);
        if (BIAS) bb = *(const float4*)(bias + c0);
        #pragma unroll
        for (int i = 0; i < 4; ++i) {
            int r = r0 + i;
            if (r < n) {
                float4 o = make_float4(acc[i][0] + bb.x, acc[i][1] + bb.y,
                                       acc[i][2] + bb.z, acc[i][3] + bb.w);
                *(float4*)(Y + (size_t)r * OUT_F + c0) = o;
            }
        }
    }
}

// ---------------- gather aggregation (one 64-lane wave per node, 64 cols) ----------------
// out[i,c] = act( dis_i^2 * v[i,c] + sum_j wn_j * v[src_j, c]  (+ b[c]) )

template<bool RELU_BIAS>
__global__ void gather64_kernel(const float* __restrict__ v, const int* __restrict__ rowptr,
                                const int* __restrict__ srcs, const float* __restrict__ wn,
                                const float* __restrict__ dis, const float* __restrict__ b,
                                float* __restrict__ out, int n) {
    int wid = __builtin_amdgcn_readfirstlane((blockIdx.x * blockDim.x + threadIdx.x) >> 6);
    int lane = threadIdx.x & 63;
    if (wid >= n) return;  // wave-uniform
    int beg = __builtin_amdgcn_readfirstlane(rowptr[wid]);
    int end = __builtin_amdgcn_readfirstlane(rowptr[wid + 1]);
    float di = dis[wid];
    float acc = v[(size_t)wid * 64 + lane] * (di * di);
    int j = beg;
    for (; j + 4 <= end; j += 4) {
        int s0 = srcs[j], s1 = srcs[j + 1], s2 = srcs[j + 2], s3 = srcs[j + 3];
        float w0 = wn[j], w1 = wn[j + 1], w2 = wn[j + 2], w3 = wn[j + 3];
        float v0 = v[(size_t)s0 * 64 + lane];
        float v1 = v[(size_t)s1 * 64 + lane];
        float v2 = v[(size_t)s2 * 64 + lane];
        float v3 = v[(size_t)s3 * 64 + lane];
        acc = fmaf(v0, w0, acc);
        acc = fmaf(v1, w1, acc);
        acc = fmaf(v2, w2, acc);
        acc = fmaf(v3, w3, acc);
    }
    for (; j < end; ++j) acc = fmaf(v[(size_t)srcs[j] * 64 + lane], wn[j], acc);
    if (RELU_BIAS) acc = fmaxf(acc + b[lane], 0.f);
    out[(size_t)wid * 64 + lane] = acc;
}

// out[i,:] = log_softmax(z[i,:]) over 40 cols; one wave per row
__global__ void logsoftmax_kernel(const float* __restrict__ z, float* __restrict__ out, int n) {
    int wid = (blockIdx.x * blockDim.x + threadIdx.x) >> 6;
    int lane = threadIdx.x & 63;
    if (wid >= n) return;
    float zz = (lane < 40) ? z[(size_t)wid * 40 + lane] : -INFINITY;
    float v = zz;
    #pragma unroll
    for (int off = 32; off > 0; off >>= 1) v = fmaxf(v, __shfl_xor(v, off));
    float ex = (lane < 40) ? expf(zz - v) : 0.f;
    float s = ex;
    #pragma unroll
    for (int off = 32; off > 0; off >>= 1) s += __shfl_xor(s, off);
    float ls = logf(s);
    if (lane < 40) out[(size_t)wid * 40 + lane] = zz - v - ls;
}

// ---------------- launch ----------------

extern "C" void kernel_launch(void* const* d_in, const int* in_sizes, int n_in,
                              void* d_out, int out_size, void* d_ws, size_t ws_size,
                              hipStream_t stream) {
    const float* x  = (const float*)d_in[0];
    const int*   ei = (const int*)d_in[1];   // [2, E] int32
    const float* W1 = (const float*)d_in[2]; // [128, 64]
    const float* b1 = (const float*)d_in[3]; // [64]
    const float* W2 = (const float*)d_in[4]; // [64, 40]
    const float* b2 = (const float*)d_in[5]; // [40]
    float* out = (float*)d_out;              // [n, 40]

    const int n = in_sizes[0] / 128;
    const int e = in_sizes[1] / 2;
    const int* src = ei;
    const int* dst = ei + e;

    // workspace layout:
    //   dis[n] f32 | counts/next[n] i32 | rowptr[n+1] i32 | bsums[1024] i32 |
    //   srcs[e] i32 | wn[e] f32 | A[n*64] f32 | B[n*64] f32     (~65 MB)
    float* dis  = (float*)d_ws;
    int* counts = (int*)(dis + n);           // reused as fill cursor 'next'
    int* rowptr = counts + n;
    int* bsums  = rowptr + (n + 1);
    int* srcs   = bsums + SCAN_B;
    float* wn   = (float*)(srcs + e);
    float* A    = wn + e;                    // xw1, then G (aggregated H)
    float* B    = A + (size_t)n * 64;        // H, then z (n x 40)

    const int T = 256;
    const int nb = (n + SCAN_B - 1) / SCAN_B;

    // --- CSR build + normalization ---
    zero_counts_kernel<<<(n + T - 1) / T, T, 0, stream>>>(counts, n);
    hist_kernel<<<(e + T - 1) / T, T, 0, stream>>>(dst, counts, e);
    dis_kernel<<<(n + T - 1) / T, T, 0, stream>>>(counts, dis, n);
    scan1_kernel<<<nb, SCAN_B, 0, stream>>>(counts, rowptr, bsums, n);
    scan2_kernel<<<1, SCAN_B, 0, stream>>>(bsums, nb);
    scan3_kernel<<<(n + T - 1) / T, T, 0, stream>>>(rowptr, counts, bsums, n, e);
    fill_kernel<<<(e + T - 1) / T, T, 0, stream>>>(src, dst, counts, dis, srcs, wn, e);

    // --- layer 1: xw1 = x@W1 ; H = relu(aggregate(xw1) + b1) ---
    gemm_tile_kernel<128, 64, false><<<(n + 63) / 64, 256, 0, stream>>>(x, W1, nullptr, A, n);
    gather64_kernel<true><<<(n * 64 + T - 1) / T, T, 0, stream>>>(A, rowptr, srcs, wn, dis, b1, B, n);

    // --- layer 2 (reassociated): G = aggregate(H); z = G@W2 + b2; out = log_softmax(z) ---
    gather64_kernel<false><<<(n * 64 + T - 1) / T, T, 0, stream>>>(B, rowptr, srcs, wn, dis, nullptr, A, n);
    gemm_tile_kernel<64, 40, true><<<(n + 63) / 64, 256, 0, stream>>>(A, W2, b2, B, n);
    logsoftmax_kernel<<<(n * 64 + T - 1) / T, T, 0, stream>>>(B, out, n);
}

// Round 4
// 498.933 us; speedup vs baseline: 2.5943x; 2.5943x over previous
//
#include <hip/hip_runtime.h>
#include <math.h>

#define SCAN_B 1024

// ---------------- CSR build ----------------

__global__ void zero_counts_kernel(int* __restrict__ c, int n) {
    int i = blockIdx.x * blockDim.x + threadIdx.x;
    if (i < n) c[i] = 0;
}

__global__ void hist_kernel(const int* __restrict__ dst, int* __restrict__ counts, int e) {
    int i = blockIdx.x * blockDim.x + threadIdx.x;
    if (i < e) atomicAdd(&counts[dst[i]], 1);
}

// dis[i] = rsqrt(deg_in + 1)   (self-loop included)
__global__ void dis_kernel(const int* __restrict__ counts, float* __restrict__ dis, int n) {
    int i = blockIdx.x * blockDim.x + threadIdx.x;
    if (i < n) dis[i] = rsqrtf((float)counts[i] + 1.0f);
}

// block-local exclusive scan of counts -> rowptr ; block totals -> bsums
__global__ void scan1_kernel(const int* __restrict__ counts, int* __restrict__ rowptr,
                             int* __restrict__ bsums, int n) {
    __shared__ int tmp[SCAN_B];
    int tid = threadIdx.x;
    int i = blockIdx.x * SCAN_B + tid;
    int v = (i < n) ? counts[i] : 0;
    tmp[tid] = v;
    __syncthreads();
    #pragma unroll
    for (int off = 1; off < SCAN_B; off <<= 1) {
        int t = (tid >= off) ? tmp[tid - off] : 0;
        __syncthreads();
        tmp[tid] += t;
        __syncthreads();
    }
    if (i < n) rowptr[i] = tmp[tid] - v;          // exclusive within block
    if (tid == SCAN_B - 1) bsums[blockIdx.x] = tmp[tid];
}

// single-block exclusive scan of bsums (nb <= SCAN_B)
__global__ void scan2_kernel(int* __restrict__ bsums, int nb) {
    __shared__ int tmp[SCAN_B];
    int tid = threadIdx.x;
    int v = (tid < nb) ? bsums[tid] : 0;
    tmp[tid] = v;
    __syncthreads();
    #pragma unroll
    for (int off = 1; off < SCAN_B; off <<= 1) {
        int t = (tid >= off) ? tmp[tid - off] : 0;
        __syncthreads();
        tmp[tid] += t;
        __syncthreads();
    }
    if (tid < nb) bsums[tid] = tmp[tid] - v;
}

// add block offsets; copy to fill-cursor array; write rowptr[n]=e
__global__ void scan3_kernel(int* __restrict__ rowptr, int* __restrict__ next,
                             const int* __restrict__ bsums, int n, int e) {
    int i = blockIdx.x * blockDim.x + threadIdx.x;
    if (i < n) {
        int r = rowptr[i] + bsums[i / SCAN_B];
        rowptr[i] = r;
        next[i] = r;
    }
    if (i == 0) rowptr[n] = e;
}

// bucket-fill: srcs sorted by dst, plus per-edge normalized weight
__global__ void fill_kernel(const int* __restrict__ src, const int* __restrict__ dst,
                            int* __restrict__ next, const float* __restrict__ dis,
                            int* __restrict__ srcs, float* __restrict__ wn, int e) {
    int i = blockIdx.x * blockDim.x + threadIdx.x;
    if (i < e) {
        int s = src[i], d = dst[i];
        int pos = atomicAdd(&next[d], 1);
        srcs[pos] = s;
        wn[pos] = dis[s] * dis[d];
    }
}

// ---------------- register-tiled GEMM: Y[n,OUT] = X[n,IN] @ W[IN,OUT] (+bias) ----------------
// block = 256 threads -> 64 rows x 64 (padded) cols; thread = 4x4 tile.
// k-loop kept at unroll 1 to hold VGPR count down (round-3 spill post-mortem:
// compiler unrolled 32 iters, 256 VGPR, 1.9 GB scratch traffic).

template<int IN_F, int OUT_F, bool BIAS>
__global__ __launch_bounds__(256) void gemm_tile_kernel(const float* __restrict__ X,
                                                        const float* __restrict__ W,
                                                        const float* __restrict__ bias,
                                                        float* __restrict__ Y, int n) {
    constexpr int PC = 64;  // padded col count
    __shared__ float Wl[IN_F * PC];
    int tid = threadIdx.x;
    for (int idx = tid; idx < IN_F * PC; idx += 256) {
        int k = idx / PC, c = idx % PC;
        Wl[idx] = (c < OUT_F) ? W[k * OUT_F + c] : 0.f;
    }
    __syncthreads();
    int tx = tid & 15;   // col group (4 cols)
    int ty = tid >> 4;   // row group (4 rows)
    int r0 = blockIdx.x * 64 + ty * 4;
    int c0 = tx * 4;
    // clamped row pointers: always in-bounds, no per-iteration select
    const float* xr[4];
    #pragma unroll
    for (int i = 0; i < 4; ++i) {
        int r = r0 + i;
        if (r >= n) r = n - 1;
        xr[i] = X + (size_t)r * IN_F;
    }
    float acc[4][4] = {};
    const float4* Wv = (const float4*)Wl;  // index: k*16 + tx
    #pragma unroll 1
    for (int k = 0; k < IN_F; k += 4) {
        float4 xv[4];
        #pragma unroll
        for (int i = 0; i < 4; ++i) xv[i] = *(const float4*)(xr[i] + k);
        #pragma unroll
        for (int j = 0; j < 4; ++j) {
            float4 wv = Wv[(k + j) * 16 + tx];
            #pragma unroll
            for (int i = 0; i < 4; ++i) {
                float xs = (j == 0) ? xv[i].x : (j == 1) ? xv[i].y : (j == 2) ? xv[i].z : xv[i].w;
                acc[i][0] = fmaf(xs, wv.x, acc[i][0]);
                acc[i][1] = fmaf(xs, wv.y, acc[i][1]);
                acc[i][2] = fmaf(xs, wv.z, acc[i][2]);
                acc[i][3] = fmaf(xs, wv.w, acc[i][3]);
            }
        }
    }
    if (c0 < OUT_F) {
        float4 bb = make_float4(0.f, 0.f, 0.f, 0.f);
        if (BIAS) bb = *(const float4*)(bias + c0);
        #pragma unroll
        for (int i = 0; i < 4; ++i) {
            int r = r0 + i;
            if (r < n) {
                float4 o = make_float4(acc[i][0] + bb.x, acc[i][1] + bb.y,
                                       acc[i][2] + bb.z, acc[i][3] + bb.w);
                *(float4*)(Y + (size_t)r * OUT_F + c0) = o;
            }
        }
    }
}

// ---------------- gather aggregation (one 64-lane wave per node, 64 cols) ----------------
// out[i,c] = act( dis_i^2 * v[i,c] + sum_j wn_j * v[src_j, c]  (+ b[c]) )

template<bool RELU_BIAS>
__global__ void gather64_kernel(const float* __restrict__ v, const int* __restrict__ rowptr,
                                const int* __restrict__ srcs, const float* __restrict__ wn,
                                const float* __restrict__ dis, const float* __restrict__ b,
                                float* __restrict__ out, int n) {
    int wid = __builtin_amdgcn_readfirstlane((blockIdx.x * blockDim.x + threadIdx.x) >> 6);
    int lane = threadIdx.x & 63;
    if (wid >= n) return;  // wave-uniform
    int beg = __builtin_amdgcn_readfirstlane(rowptr[wid]);
    int end = __builtin_amdgcn_readfirstlane(rowptr[wid + 1]);
    float di = dis[wid];
    float acc = v[(size_t)wid * 64 + lane] * (di * di);
    int j = beg;
    for (; j + 4 <= end; j += 4) {
        int s0 = srcs[j], s1 = srcs[j + 1], s2 = srcs[j + 2], s3 = srcs[j + 3];
        float w0 = wn[j], w1 = wn[j + 1], w2 = wn[j + 2], w3 = wn[j + 3];
        float v0 = v[(size_t)s0 * 64 + lane];
        float v1 = v[(size_t)s1 * 64 + lane];
        float v2 = v[(size_t)s2 * 64 + lane];
        float v3 = v[(size_t)s3 * 64 + lane];
        acc = fmaf(v0, w0, acc);
        acc = fmaf(v1, w1, acc);
        acc = fmaf(v2, w2, acc);
        acc = fmaf(v3, w3, acc);
    }
    for (; j < end; ++j) acc = fmaf(v[(size_t)srcs[j] * 64 + lane], wn[j], acc);
    if (RELU_BIAS) acc = fmaxf(acc + b[lane], 0.f);
    out[(size_t)wid * 64 + lane] = acc;
}

// out[i,:] = log_softmax(z[i,:]) over 40 cols; one wave per row
__global__ void logsoftmax_kernel(const float* __restrict__ z, float* __restrict__ out, int n) {
    int wid = (blockIdx.x * blockDim.x + threadIdx.x) >> 6;
    int lane = threadIdx.x & 63;
    if (wid >= n) return;
    float zz = (lane < 40) ? z[(size_t)wid * 40 + lane] : -INFINITY;
    float v = zz;
    #pragma unroll
    for (int off = 32; off > 0; off >>= 1) v = fmaxf(v, __shfl_xor(v, off));
    float ex = (lane < 40) ? expf(zz - v) : 0.f;
    float s = ex;
    #pragma unroll
    for (int off = 32; off > 0; off >>= 1) s += __shfl_xor(s, off);
    float ls = logf(s);
    if (lane < 40) out[(size_t)wid * 40 + lane] = zz - v - ls;
}

// ---------------- launch ----------------

extern "C" void kernel_launch(void* const* d_in, const int* in_sizes, int n_in,
                              void* d_out, int out_size, void* d_ws, size_t ws_size,
                              hipStream_t stream) {
    const float* x  = (const float*)d_in[0];
    const int*   ei = (const int*)d_in[1];   // [2, E] int32
    const float* W1 = (const float*)d_in[2]; // [128, 64]
    const float* b1 = (const float*)d_in[3]; // [64]
    const float* W2 = (const float*)d_in[4]; // [64, 40]
    const float* b2 = (const float*)d_in[5]; // [40]
    float* out = (float*)d_out;              // [n, 40]

    const int n = in_sizes[0] / 128;
    const int e = in_sizes[1] / 2;
    const int* src = ei;
    const int* dst = ei + e;

    // workspace layout:
    //   dis[n] f32 | counts/next[n] i32 | rowptr[n+1] i32 | bsums[1024] i32 |
    //   srcs[e] i32 | wn[e] f32 | A[n*64] f32 | B[n*64] f32     (~65 MB)
    float* dis  = (float*)d_ws;
    int* counts = (int*)(dis + n);           // reused as fill cursor 'next'
    int* rowptr = counts + n;
    int* bsums  = rowptr + (n + 1);
    int* srcs   = bsums + SCAN_B;
    float* wn   = (float*)(srcs + e);
    float* A    = wn + e;                    // xw1, then G (aggregated H)
    float* B    = A + (size_t)n * 64;        // H, then z (n x 40)

    const int T = 256;
    const int nb = (n + SCAN_B - 1) / SCAN_B;

    // --- CSR build + normalization ---
    zero_counts_kernel<<<(n + T - 1) / T, T, 0, stream>>>(counts, n);
    hist_kernel<<<(e + T - 1) / T, T, 0, stream>>>(dst, counts, e);
    dis_kernel<<<(n + T - 1) / T, T, 0, stream>>>(counts, dis, n);
    scan1_kernel<<<nb, SCAN_B, 0, stream>>>(counts, rowptr, bsums, n);
    scan2_kernel<<<1, SCAN_B, 0, stream>>>(bsums, nb);
    scan3_kernel<<<(n + T - 1) / T, T, 0, stream>>>(rowptr, counts, bsums, n, e);
    fill_kernel<<<(e + T - 1) / T, T, 0, stream>>>(src, dst, counts, dis, srcs, wn, e);

    // --- layer 1: xw1 = x@W1 ; H = relu(aggregate(xw1) + b1) ---
    gemm_tile_kernel<128, 64, false><<<(n + 63) / 64, 256, 0, stream>>>(x, W1, nullptr, A, n);
    gather64_kernel<true><<<(n * 64 + T - 1) / T, T, 0, stream>>>(A, rowptr, srcs, wn, dis, b1, B, n);

    // --- layer 2 (reassociated): G = aggregate(H); z = G@W2 + b2; out = log_softmax(z) ---
    gather64_kernel<false><<<(n * 64 + T - 1) / T, T, 0, stream>>>(B, rowptr, srcs, wn, dis, nullptr, A, n);
    gemm_tile_kernel<64, 40, true><<<(n + 63) / 64, 256, 0, stream>>>(A, W2, b2, B, n);
    logsoftmax_kernel<<<(n * 64 + T - 1) / T, T, 0, stream>>>(B, out, n);
}

// Round 5
// 442.528 us; speedup vs baseline: 2.9249x; 1.1275x over previous
//
#include <hip/hip_runtime.h>
#include <math.h>

#define SCAN_B 1024

typedef unsigned short u16;
typedef unsigned int u32;

// bf16 <-> f32 (bf16 = truncated f32; up-convert is an exact shift)
__device__ inline float bf2f(u16 u) {
    union { u32 i; float f; } c; c.i = ((u32)u) << 16; return c.f;
}
__device__ inline u16 f2bf(float f) {  // round-to-nearest-even
    union { float f; u32 i; } c; c.f = f;
    u32 r = c.i + 0x7FFFu + ((c.i >> 16) & 1u);
    return (u16)(r >> 16);
}

// ---------------- CSR build ----------------

__global__ void zero_counts_kernel(int* __restrict__ c, int n) {
    int i = blockIdx.x * blockDim.x + threadIdx.x;
    if (i < n) c[i] = 0;
}

__global__ void hist_kernel(const int* __restrict__ dst, int* __restrict__ counts, int e) {
    int i = blockIdx.x * blockDim.x + threadIdx.x;
    if (i < e) atomicAdd(&counts[dst[i]], 1);
}

// block-local exclusive scan of counts -> rowptr ; block totals -> bsums ; dis fused
__global__ void scan1_kernel(const int* __restrict__ counts, int* __restrict__ rowptr,
                             int* __restrict__ bsums, float* __restrict__ dis, int n) {
    __shared__ int tmp[SCAN_B];
    int tid = threadIdx.x;
    int i = blockIdx.x * SCAN_B + tid;
    int v = (i < n) ? counts[i] : 0;
    if (i < n) dis[i] = rsqrtf((float)v + 1.0f);   // self-loop included
    tmp[tid] = v;
    __syncthreads();
    #pragma unroll
    for (int off = 1; off < SCAN_B; off <<= 1) {
        int t = (tid >= off) ? tmp[tid - off] : 0;
        __syncthreads();
        tmp[tid] += t;
        __syncthreads();
    }
    if (i < n) rowptr[i] = tmp[tid] - v;           // exclusive within block
    if (tid == SCAN_B - 1) bsums[blockIdx.x] = tmp[tid];
}

// single-block exclusive scan of bsums (nb <= SCAN_B)
__global__ void scan2_kernel(int* __restrict__ bsums, int nb) {
    __shared__ int tmp[SCAN_B];
    int tid = threadIdx.x;
    int v = (tid < nb) ? bsums[tid] : 0;
    tmp[tid] = v;
    __syncthreads();
    #pragma unroll
    for (int off = 1; off < SCAN_B; off <<= 1) {
        int t = (tid >= off) ? tmp[tid - off] : 0;
        __syncthreads();
        tmp[tid] += t;
        __syncthreads();
    }
    if (tid < nb) bsums[tid] = tmp[tid] - v;
}

// add block offsets; copy to fill-cursor array; write rowptr[n]=e
__global__ void scan3_kernel(int* __restrict__ rowptr, int* __restrict__ next,
                             const int* __restrict__ bsums, int n, int e) {
    int i = blockIdx.x * blockDim.x + threadIdx.x;
    if (i < n) {
        int r = rowptr[i] + bsums[i / SCAN_B];
        rowptr[i] = r;
        next[i] = r;
    }
    if (i == 0) rowptr[n] = e;
}

// bucket-fill: single 8B record per edge {src, bits(wn)} — halves scattered lines
__global__ void fill_kernel(const int* __restrict__ src, const int* __restrict__ dst,
                            int* __restrict__ next, const float* __restrict__ dis,
                            int2* __restrict__ erec, int e) {
    int i = blockIdx.x * blockDim.x + threadIdx.x;
    if (i < e) {
        int s = src[i], d = dst[i];
        float w = dis[s] * dis[d];
        int pos = atomicAdd(&next[d], 1);
        erec[pos] = make_int2(s, __float_as_int(w));
    }
}

// ---------------- register-tiled GEMM: Y[n,OUT] = X[n,IN] @ W[IN,OUT] (+bias) ----------------
// block = 256 threads -> 64 rows x 64 (padded) cols; thread = 4x4 tile.
// k-loop kept at unroll 1 (round-3 post-mortem: full unroll -> 256 VGPR spill).

__device__ inline float4 load4(const float* p) { return *(const float4*)p; }
__device__ inline float4 load4(const u16* p) {
    ushort4 u = *(const ushort4*)p;
    return make_float4(bf2f(u.x), bf2f(u.y), bf2f(u.z), bf2f(u.w));
}

template<typename XT, typename YT, int IN_F, int OUT_F, bool BIAS>
__global__ __launch_bounds__(256) void gemm_tile_kernel(const XT* __restrict__ X,
                                                        const float* __restrict__ W,
                                                        const float* __restrict__ bias,
                                                        YT* __restrict__ Y, int n) {
    constexpr int PC = 64;  // padded col count
    __shared__ float Wl[IN_F * PC];
    int tid = threadIdx.x;
    for (int idx = tid; idx < IN_F * PC; idx += 256) {
        int k = idx / PC, c = idx % PC;
        Wl[idx] = (c < OUT_F) ? W[k * OUT_F + c] : 0.f;
    }
    __syncthreads();
    int tx = tid & 15;   // col group (4 cols)
    int ty = tid >> 4;   // row group (4 rows)
    int r0 = blockIdx.x * 64 + ty * 4;
    int c0 = tx * 4;
    // clamped row pointers: always in-bounds, no per-iteration select
    const XT* xr[4];
    #pragma unroll
    for (int i = 0; i < 4; ++i) {
        int r = r0 + i;
        if (r >= n) r = n - 1;
        xr[i] = X + (size_t)r * IN_F;
    }
    float acc[4][4] = {};
    const float4* Wv = (const float4*)Wl;  // index: k*16 + tx
    #pragma unroll 1
    for (int k = 0; k < IN_F; k += 4) {
        float4 xv[4];
        #pragma unroll
        for (int i = 0; i < 4; ++i) xv[i] = load4(xr[i] + k);
        #pragma unroll
        for (int j = 0; j < 4; ++j) {
            float4 wv = Wv[(k + j) * 16 + tx];
            #pragma unroll
            for (int i = 0; i < 4; ++i) {
                float xs = (j == 0) ? xv[i].x : (j == 1) ? xv[i].y : (j == 2) ? xv[i].z : xv[i].w;
                acc[i][0] = fmaf(xs, wv.x, acc[i][0]);
                acc[i][1] = fmaf(xs, wv.y, acc[i][1]);
                acc[i][2] = fmaf(xs, wv.z, acc[i][2]);
                acc[i][3] = fmaf(xs, wv.w, acc[i][3]);
            }
        }
    }
    if (c0 < OUT_F) {
        float4 bb = make_float4(0.f, 0.f, 0.f, 0.f);
        if (BIAS) bb = *(const float4*)(bias + c0);
        #pragma unroll
        for (int i = 0; i < 4; ++i) {
            int r = r0 + i;
            if (r < n) {
                if constexpr (sizeof(YT) == 2) {
                    ushort4 o;
                    o.x = f2bf(acc[i][0] + bb.x);
                    o.y = f2bf(acc[i][1] + bb.y);
                    o.z = f2bf(acc[i][2] + bb.z);
                    o.w = f2bf(acc[i][3] + bb.w);
                    *(ushort4*)(Y + (size_t)r * OUT_F + c0) = o;
                } else {
                    float4 o = make_float4(acc[i][0] + bb.x, acc[i][1] + bb.y,
                                           acc[i][2] + bb.z, acc[i][3] + bb.w);
                    *(float4*)(Y + (size_t)r * OUT_F + c0) = o;
                }
            }
        }
    }
}

// ---------------- gather aggregation (one 64-lane wave per node, 64 bf16 cols) ----------------
// out[i,c] = act( dis_i^2 * v[i,c] + sum_j wn_j * v[src_j, c]  (+ b[c]) )

template<bool RELU_BIAS>
__global__ void gather64_kernel(const u16* __restrict__ v, const int* __restrict__ rowptr,
                                const int2* __restrict__ erec, const float* __restrict__ dis,
                                const float* __restrict__ b, u16* __restrict__ out, int n) {
    int wid = __builtin_amdgcn_readfirstlane((blockIdx.x * blockDim.x + threadIdx.x) >> 6);
    int lane = threadIdx.x & 63;
    if (wid >= n) return;  // wave-uniform
    int beg = __builtin_amdgcn_readfirstlane(rowptr[wid]);
    int end = __builtin_amdgcn_readfirstlane(rowptr[wid + 1]);
    float di = dis[wid];
    float acc = bf2f(v[(size_t)wid * 64 + lane]) * (di * di);
    int j = beg;
    for (; j + 4 <= end; j += 4) {
        int2 e0 = erec[j], e1 = erec[j + 1], e2 = erec[j + 2], e3 = erec[j + 3];
        float v0 = bf2f(v[(size_t)e0.x * 64 + lane]);
        float v1 = bf2f(v[(size_t)e1.x * 64 + lane]);
        float v2 = bf2f(v[(size_t)e2.x * 64 + lane]);
        float v3 = bf2f(v[(size_t)e3.x * 64 + lane]);
        acc = fmaf(v0, __int_as_float(e0.y), acc);
        acc = fmaf(v1, __int_as_float(e1.y), acc);
        acc = fmaf(v2, __int_as_float(e2.y), acc);
        acc = fmaf(v3, __int_as_float(e3.y), acc);
    }
    for (; j < end; ++j) {
        int2 ee = erec[j];
        acc = fmaf(bf2f(v[(size_t)ee.x * 64 + lane]), __int_as_float(ee.y), acc);
    }
    if (RELU_BIAS) acc = fmaxf(acc + b[lane], 0.f);
    out[(size_t)wid * 64 + lane] = f2bf(acc);
}

// out[i,:] = log_softmax(z[i,:]) over 40 cols; one wave per row
__global__ void logsoftmax_kernel(const float* __restrict__ z, float* __restrict__ out, int n) {
    int wid = (blockIdx.x * blockDim.x + threadIdx.x) >> 6;
    int lane = threadIdx.x & 63;
    if (wid >= n) return;
    float zz = (lane < 40) ? z[(size_t)wid * 40 + lane] : -INFINITY;
    float v = zz;
    #pragma unroll
    for (int off = 32; off > 0; off >>= 1) v = fmaxf(v, __shfl_xor(v, off));
    float ex = (lane < 40) ? expf(zz - v) : 0.f;
    float s = ex;
    #pragma unroll
    for (int off = 32; off > 0; off >>= 1) s += __shfl_xor(s, off);
    float ls = logf(s);
    if (lane < 40) out[(size_t)wid * 40 + lane] = zz - v - ls;
}

// ---------------- launch ----------------

extern "C" void kernel_launch(void* const* d_in, const int* in_sizes, int n_in,
                              void* d_out, int out_size, void* d_ws, size_t ws_size,
                              hipStream_t stream) {
    const float* x  = (const float*)d_in[0];
    const int*   ei = (const int*)d_in[1];   // [2, E] int32
    const float* W1 = (const float*)d_in[2]; // [128, 64]
    const float* b1 = (const float*)d_in[3]; // [64]
    const float* W2 = (const float*)d_in[4]; // [64, 40]
    const float* b2 = (const float*)d_in[5]; // [40]
    float* out = (float*)d_out;              // [n, 40]

    const int n = in_sizes[0] / 128;
    const int e = in_sizes[1] / 2;
    const int* src = ei;
    const int* dst = ei + e;

    // workspace layout (8B-aligned blocks):
    //   erec[e] int2 | dis[n] f32 | counts/next[n] i32 | rowptr[n+2] i32 |
    //   bsums[1024] i32 | A[n*64] bf16 | B[n*64] bf16 | Z[n*40] f32    (~56 MB)
    int2* erec  = (int2*)d_ws;
    float* dis  = (float*)(erec + e);
    int* counts = (int*)(dis + n);           // reused as fill cursor 'next'
    int* rowptr = counts + n;
    int* bsums  = rowptr + (n + 2);          // +2 keeps later blocks 8B-aligned
    u16* A      = (u16*)(bsums + SCAN_B);    // xw1 (bf16), then G (aggregated H)
    u16* B      = A + (size_t)n * 64;        // H (bf16)
    float* Z    = (float*)(B + (size_t)n * 64);  // logits (n x 40, f32)

    const int T = 256;
    const int nb = (n + SCAN_B - 1) / SCAN_B;

    // --- CSR build + normalization ---
    zero_counts_kernel<<<(n + T - 1) / T, T, 0, stream>>>(counts, n);
    hist_kernel<<<(e + T - 1) / T, T, 0, stream>>>(dst, counts, e);
    scan1_kernel<<<nb, SCAN_B, 0, stream>>>(counts, rowptr, bsums, dis, n);
    scan2_kernel<<<1, SCAN_B, 0, stream>>>(bsums, nb);
    scan3_kernel<<<(n + T - 1) / T, T, 0, stream>>>(rowptr, counts, bsums, n, e);
    fill_kernel<<<(e + T - 1) / T, T, 0, stream>>>(src, dst, counts, dis, erec, e);

    // --- layer 1: xw1 = x@W1 (bf16) ; H = relu(aggregate(xw1) + b1) (bf16) ---
    gemm_tile_kernel<float, u16, 128, 64, false>
        <<<(n + 63) / 64, 256, 0, stream>>>(x, W1, nullptr, A, n);
    gather64_kernel<true><<<(n * 64 + T - 1) / T, T, 0, stream>>>(A, rowptr, erec, dis, b1, B, n);

    // --- layer 2 (reassociated): G = aggregate(H) (bf16); Z = G@W2 + b2; out = log_softmax(Z) ---
    gather64_kernel<false><<<(n * 64 + T - 1) / T, T, 0, stream>>>(B, rowptr, erec, dis, nullptr, A, n);
    gemm_tile_kernel<u16, float, 64, 40, true>
        <<<(n + 63) / 64, 256, 0, stream>>>(A, W2, b2, Z, n);
    logsoftmax_kernel<<<(n * 64 + T - 1) / T, T, 0, stream>>>(Z, out, n);
}